// Round 3
// baseline (416.170 us; speedup 1.0000x reference)
//
#include <hip/hip_runtime.h>
#include <cstdint>

// ---------------------------------------------------------------------------
// InvariantPointAttention fused kernel set for MI355X (gfx950)
// N=768, C_S=384, C_Z=128, C_IPA=16, H=12, NQ=4, NV=8
// ---------------------------------------------------------------------------

typedef __attribute__((ext_vector_type(8))) short short8;
typedef __attribute__((ext_vector_type(4))) short short4_t;
typedef __attribute__((ext_vector_type(4))) float f32x4;

__device__ __forceinline__ unsigned short f2bf(float f) {
    unsigned u = __float_as_uint(f);
    u = (u + 0x7FFFu + ((u >> 16) & 1u)) >> 16;   // RNE
    return (unsigned short)u;
}
__device__ __forceinline__ float bf2f(unsigned short s) {
    return __uint_as_float(((unsigned)s) << 16);
}
__device__ __forceinline__ unsigned pk2(float lo, float hi) {
    return (unsigned)f2bf(lo) | ((unsigned)f2bf(hi) << 16);
}

// ---------------------------------------------------------------------------
// Kernel 1: fused projection GEMM.  s (768x384) @ [Wq|Wkv|Wq3|Wkv3] (384x1152)
// ---------------------------------------------------------------------------
__global__ __launch_bounds__(256) void proj_kernel(
    const float* __restrict__ s,
    const float* __restrict__ Wq,   const float* __restrict__ bq,
    const float* __restrict__ Wkv,  const float* __restrict__ bkv,
    const float* __restrict__ Wq3,  const float* __restrict__ bq3,
    const float* __restrict__ Wkv3, const float* __restrict__ bkv3,
    float* __restrict__ Qw, unsigned short* __restrict__ Kw,
    unsigned short* __restrict__ Vw,
    float* __restrict__ P3q, float* __restrict__ P3kv)
{
    __shared__ __align__(16) float s_lds[32 * 384];
    const int t  = threadIdx.x;
    const int r0 = blockIdx.x * 32;
    const int c0 = blockIdx.y * 128;

    for (int u = t; u < 3072; u += 256) {
        int r = u / 96, c4 = u - r * 96;
        *(float4*)&s_lds[r * 384 + c4 * 4] =
            *(const float4*)&s[(size_t)(r0 + r) * 384 + c4 * 4];
    }
    __syncthreads();

    const int rg = t >> 6;
    const int lc = t & 63;
    const int colA = c0 + lc;
    const int colB = c0 + lc + 64;

    const float *wpA, *wpB; int ldA, ldB; float biasA, biasB;
    {
        int col = colA;
        if (col < 192)      { wpA = Wq   + col;       ldA = 192; biasA = bq[col]; }
        else if (col < 576) { wpA = Wkv  + (col-192); ldA = 384; biasA = bkv[col-192]; }
        else if (col < 720) { wpA = Wq3  + (col-576); ldA = 144; biasA = bq3[col-576]; }
        else                { wpA = Wkv3 + (col-720); ldA = 432; biasA = bkv3[col-720]; }
        col = colB;
        if (col < 192)      { wpB = Wq   + col;       ldB = 192; biasB = bq[col]; }
        else if (col < 576) { wpB = Wkv  + (col-192); ldB = 384; biasB = bkv[col-192]; }
        else if (col < 720) { wpB = Wq3  + (col-576); ldB = 144; biasB = bq3[col-576]; }
        else                { wpB = Wkv3 + (col-720); ldB = 432; biasB = bkv3[col-720]; }
    }

    float acc0[8] = {}, acc1[8] = {};
    for (int k = 0; k < 384; k += 4) {
        float4 sv[8];
        #pragma unroll
        for (int r = 0; r < 8; r++)
            sv[r] = *(const float4*)&s_lds[(rg*8 + r) * 384 + k];
        #pragma unroll
        for (int kk = 0; kk < 4; kk++) {
            float w0 = wpA[(k + kk) * ldA];
            float w1 = wpB[(k + kk) * ldB];
            #pragma unroll
            for (int r = 0; r < 8; r++) {
                float sval = ((const float*)&sv[r])[kk];
                acc0[r] += sval * w0;
                acc1[r] += sval * w1;
            }
        }
    }

    #pragma unroll
    for (int q = 0; q < 2; q++) {
        int col   = q ? colB : colA;
        float bia = q ? biasB : biasA;
        #pragma unroll
        for (int r = 0; r < 8; r++) {
            int row = r0 + rg*8 + r;
            float v = (q ? acc1[r] : acc0[r]) + bia;
            if (col < 192) {
                Qw[(size_t)row*192 + col] = v;
            } else if (col < 576) {
                int c = col - 192, h = c >> 5, sub = c & 31;
                if (sub < 16) Kw[(size_t)row*192 + h*16 + sub]      = f2bf(v);
                else          Vw[(size_t)row*192 + h*16 + (sub-16)] = f2bf(v);
            } else if (col < 720) {
                P3q[(size_t)row*144 + (col-576)] = v;
            } else {
                P3kv[(size_t)row*432 + (col-720)] = v;
            }
        }
    }
}

// ---------------------------------------------------------------------------
// Kernel 2: rotate/translate projected points.
// ---------------------------------------------------------------------------
__global__ __launch_bounds__(192) void rot3_kernel(
    const float* __restrict__ P3q, const float* __restrict__ P3kv,
    const float* __restrict__ rots, const float* __restrict__ trans,
    float* __restrict__ Q3w, unsigned short* __restrict__ K3w,
    unsigned short* __restrict__ V3w)
{
    const int n = blockIdx.x;
    const int t = threadIdx.x;
    float R[9];
    #pragma unroll
    for (int u = 0; u < 9; u++) R[u] = rots[n*9 + u];
    float T0 = trans[n*3+0], T1 = trans[n*3+1], T2 = trans[n*3+2];

    float p0, p1, p2;
    if (t < 48) {
        p0 = P3q[(size_t)n*144 + t];
        p1 = P3q[(size_t)n*144 + 48 + t];
        p2 = P3q[(size_t)n*144 + 96 + t];
    } else {
        int k = t - 48;
        p0 = P3kv[(size_t)n*432 + k];
        p1 = P3kv[(size_t)n*432 + 144 + k];
        p2 = P3kv[(size_t)n*432 + 288 + k];
    }
    float o0 = R[0]*p0 + R[1]*p1 + R[2]*p2 + T0;
    float o1 = R[3]*p0 + R[4]*p1 + R[5]*p2 + T1;
    float o2 = R[6]*p0 + R[7]*p1 + R[8]*p2 + T2;

    if (t < 48) {
        Q3w[(size_t)n*144 + t*3 + 0] = o0;
        Q3w[(size_t)n*144 + t*3 + 1] = o1;
        Q3w[(size_t)n*144 + t*3 + 2] = o2;
    } else {
        int k = t - 48, h = k / 12, m = k % 12;
        if (m < 4) {
            size_t base = (size_t)n*144 + (h*4 + m)*3;
            K3w[base+0] = f2bf(o0); K3w[base+1] = f2bf(o1); K3w[base+2] = f2bf(o2);
        } else {
            size_t base = (size_t)n*384 + (h*8 + (m-4))*4;
            V3w[base+0] = f2bf(o0); V3w[base+1] = f2bf(o1); V3w[base+2] = f2bf(o2);
        }
    }
}

// ---------------------------------------------------------------------------
// Kernel 3: fused IPA attention, j-split x2 (flash-style exact partials).
// grid 1536: block = (i, chunk).  12 z-tiles of 32 j each.
// z subtile layout: 64 subtiles of [4][16] bf16, stride 88 elems (176 B)
// -> phase-C gather groups hit disjoint bank ranges.
// Partial out per (i,chunk): [0:192) O | [192:480) O3 | [480:2016) Opair |
// [2016:2028) den   (stride 2048 f32)
// ---------------------------------------------------------------------------
__global__ __launch_bounds__(256, 6) void ipa_main(
    const float* __restrict__ z, const float* __restrict__ mask,
    const float* __restrict__ Wb, const float* __restrict__ bb,
    const float* __restrict__ hw,
    const float* __restrict__ Qw, const unsigned short* __restrict__ Kw,
    const unsigned short* __restrict__ Vw,
    const float* __restrict__ Q3w, const unsigned short* __restrict__ K3w,
    const unsigned short* __restrict__ V3w,
    float* __restrict__ part3)
{
    __shared__ __align__(16) unsigned short z_l[64 * 88];     // 11 KB
    __shared__ __align__(16) unsigned short wbT_l[16 * 136];
    __shared__ __align__(16) float          p_l[32 * 17];
    __shared__ __align__(16) unsigned short pT_l[16 * 40];
    __shared__ __align__(16) float          Q_lds[192];
    __shared__ __align__(16) float          Q3_lds[144];
    __shared__ float hw_lds[12], bb_lds[12];

    const int i     = blockIdx.x >> 1;
    const int chunk = blockIdx.x & 1;
    const int t    = threadIdx.x;
    const int lane = t & 63;
    const int wv   = t >> 6;
    const int g    = lane >> 4;
    const int lm   = lane & 15;

    // ------- per-block init -------
    if (t < 192) Q_lds[t]  = Qw[(size_t)i*192 + t];
    if (t < 144) Q3_lds[t] = Q3w[(size_t)i*144 + t];
    if (t < 12) {
        hw_lds[t] = log1pf(__expf(hw[t])) * 0.13608276348795434f;
        bb_lds[t] = bb[t];
    }
    if (t < 160) pT_l[480 + t] = 0;
    for (int u = t; u < 1536; u += 256) {
        int h = u % 12, c = u / 12;
        wbT_l[h*136 + c] = f2bf(Wb[c*12 + h]);
    }
    const float mask_i = mask[i];

    // accumulators
    f32x4 opA = {0,0,0,0}, opB = {0,0,0,0};
    float oacc = 0.0f;
    float o3x = 0, o3y = 0, o3z = 0;
    float dena = 0;
    const int oh = t >> 4, oc = t & 15;
    int o3h = -1, o3v = 0;
    if (t >= 192)     { o3h = (t - 192) >> 3; o3v = (t - 192) & 7; }
    else if (t < 32)  { o3h = 8 + (t >> 3);   o3v = t & 7; }
    const int denh = (t >= 32 && t < 44) ? (t - 32) : -1;

    // z prefetch setup: thread stages row jj (within tile), 16 floats at c16*16
    const int jj  = t >> 3, c16 = t & 7;
    const float* zbase = z + ((size_t)i*768 + chunk*384 + jj)*128 + c16*16;
    const int sidx = ((jj >> 2)*8 + c16)*88 + (jj & 3)*16;   // element index
    float4 pf0, pf1, pf2, pf3;
    pf0 = *(const float4*)(zbase + 0);
    pf1 = *(const float4*)(zbase + 4);
    pf2 = *(const float4*)(zbase + 8);
    pf3 = *(const float4*)(zbase + 12);

    __syncthreads();

    for (int tile = 0; tile < 12; tile++) {
        const int j0 = chunk*384 + tile*32;

        // ---- phase A: store staged tile, issue next prefetch ----
        {
            uint4* dst = (uint4*)&z_l[sidx];
            dst[0] = uint4{pk2(pf0.x,pf0.y), pk2(pf0.z,pf0.w), pk2(pf1.x,pf1.y), pk2(pf1.z,pf1.w)};
            dst[1] = uint4{pk2(pf2.x,pf2.y), pk2(pf2.z,pf2.w), pk2(pf3.x,pf3.y), pk2(pf3.z,pf3.w)};
        }
        if (tile + 1 < 12) {
            const float* np = zbase + (size_t)(tile + 1) * 32 * 128;
            pf0 = *(const float4*)(np + 0);
            pf1 = *(const float4*)(np + 4);
            pf2 = *(const float4*)(np + 8);
            pf3 = *(const float4*)(np + 12);
        }
        __syncthreads();

        // ---- phase B1: B = z@Wb via MFMA, waves 0 (rows 0-15) & 1 (16-31) ----
        if (wv < 2) {
            f32x4 ab = {0,0,0,0};
            const int jt = wv;
            #pragma unroll
            for (int ks = 0; ks < 4; ks++) {
                short8 bf = *(const short8*)&wbT_l[lm*136 + ks*32 + g*8];
                int jr = jt*16 + lm;
                int ch = (jr >> 2)*8 + ks*2 + (g >> 1);
                short8 a = *(const short8*)&z_l[ch*88 + (jr & 3)*16 + (g & 1)*8];
                ab = __builtin_amdgcn_mfma_f32_16x16x32_bf16(a, bf, ab, 0, 0, 0);
            }
            if (lm < 12) {
                #pragma unroll
                for (int r = 0; r < 4; r++)
                    p_l[(jt*16 + g*4 + r)*17 + lm] = ab[r];
            }
        }
        __syncthreads();

        // ---- phase B2: finish logits, exp, store p (f32) and p^T (bf16) ----
        #pragma unroll
        for (int rep = 0; rep < 2; rep++) {
            int pr = t + rep*256;
            if (pr < 384) {
                int jjq = pr / 12;
                int h   = pr - jjq*12;
                int j   = j0 + jjq;
                float Bv = p_l[jjq*17 + h];
                const unsigned short* kp = Kw + (size_t)j*192 + h*16;
                short8 kA = *(const short8*)(kp);
                short8 kB = *(const short8*)(kp + 8);
                float qk = 0.0f;
                #pragma unroll
                for (int e = 0; e < 8; e++) qk += Q_lds[h*16 + e]     * bf2f((unsigned short)kA[e]);
                #pragma unroll
                for (int e = 0; e < 8; e++) qk += Q_lds[h*16 + 8 + e] * bf2f((unsigned short)kB[e]);
                const unsigned short* k3p = K3w + (size_t)j*144 + h*12;
                short4_t c0v = *(const short4_t*)(k3p);
                short4_t c1v = *(const short4_t*)(k3p + 4);
                short4_t c2v = *(const short4_t*)(k3p + 8);
                float d2 = 0.0f;
                #pragma unroll
                for (int e = 0; e < 4; e++) { float d = Q3_lds[h*12 + e]     - bf2f((unsigned short)c0v[e]); d2 += d*d; }
                #pragma unroll
                for (int e = 0; e < 4; e++) { float d = Q3_lds[h*12 + 4 + e] - bf2f((unsigned short)c1v[e]); d2 += d*d; }
                #pragma unroll
                for (int e = 0; e < 4; e++) { float d = Q3_lds[h*12 + 8 + e] - bf2f((unsigned short)c2v[e]); d2 += d*d; }
                float mj = mask[j];
                float lg = qk * 0.14433756729740643f
                         + (Bv + bb_lds[h]) * 0.5773502691896258f
                         - 0.5f * hw_lds[h] * d2
                         + (mask_i * mj - 1.0f) * 1e9f;
                float p = __expf(lg);
                p_l[jjq*17 + h]  = p;
                pT_l[h*40 + jjq] = f2bf(p);
            }
        }
        __syncthreads();

        // ---- phase C: O_pair MFMA + O/O3/den ----
        {
            const int nt0 = wv*2;
            short8 ap = *(const short8*)((const char*)pT_l + lm*80 + g*16);
            short8 b0, b1;
            #pragma unroll
            for (int e = 0; e < 8; e++) {
                int jje = g*8 + e;
                int su  = (jje >> 2)*8;
                int ro  = (jje & 3)*16;
                b0[e] = (short)z_l[(su + nt0)     * 88 + ro + lm];
                b1[e] = (short)z_l[(su + nt0 + 1) * 88 + ro + lm];
            }
            opA = __builtin_amdgcn_mfma_f32_16x16x32_bf16(ap, b0, opA, 0, 0, 0);
            opB = __builtin_amdgcn_mfma_f32_16x16x32_bf16(ap, b1, opB, 0, 0, 0);
        }
        if (t < 192) {
            #pragma unroll 8
            for (int jjq = 0; jjq < 32; jjq++) {
                float p = p_l[jjq*17 + oh];
                oacc += p * bf2f(Vw[(size_t)(j0 + jjq)*192 + oh*16 + oc]);
            }
        }
        if (o3h >= 0) {
            #pragma unroll 8
            for (int jjq = 0; jjq < 32; jjq++) {
                float p = p_l[jjq*17 + o3h];
                short4_t v4 = *(const short4_t*)(V3w + (size_t)(j0 + jjq)*384 + (o3h*8 + o3v)*4);
                o3x += p * bf2f((unsigned short)v4[0]);
                o3y += p * bf2f((unsigned short)v4[1]);
                o3z += p * bf2f((unsigned short)v4[2]);
            }
        }
        if (denh >= 0) {
            #pragma unroll 8
            for (int jjq = 0; jjq < 32; jjq++) dena += p_l[jjq*17 + denh];
        }
        __syncthreads();
    }

    // ------- write partials -------
    float* pb = part3 + (size_t)blockIdx.x * 2048;
    if (t < 192) pb[t] = oacc;
    if (o3h >= 0) {
        int base = 192 + (o3h*8 + o3v)*3;
        pb[base+0] = o3x; pb[base+1] = o3y; pb[base+2] = o3z;
    }
    if (denh >= 0) pb[2016 + denh] = dena;
    {
        const int nt0 = wv*2;
        #pragma unroll
        for (int r = 0; r < 4; r++) {
            int h = g*4 + r;
            if (h < 12) {
                pb[480 + h*128 + nt0*16 + lm]       = opA[r];
                pb[480 + h*128 + (nt0 + 1)*16 + lm] = opB[r];
            }
        }
    }
}

// ---------------------------------------------------------------------------
// Kernel 3b: combine the 2 j-chunks, divide by den, rotate O3, write OF row.
// grid 768, block 256
// ---------------------------------------------------------------------------
__global__ __launch_bounds__(256) void combine_kernel(
    const float* __restrict__ part3, const float* __restrict__ rots,
    const float* __restrict__ trans, unsigned short* __restrict__ OF)
{
    const int i = blockIdx.x;
    const int t = threadIdx.x;
    const float* pa = part3 + (size_t)i*2*2048;
    const float* pb = pa + 2048;
    __shared__ float den_s[12];
    if (t < 12) den_s[t] = pa[2016 + t] + pb[2016 + t];
    __syncthreads();

    const size_t ofb = (size_t)i * 2112;
    if (t < 192) OF[ofb + t] = f2bf((pa[t] + pb[t]) / den_s[t >> 4]);
    if (t < 96) {
        int h = t >> 3, v = t & 7;
        float den = den_s[h];
        int base = 192 + t*3;
        float m0 = (pa[base+0] + pb[base+0]) / den - trans[i*3+0];
        float m1 = (pa[base+1] + pb[base+1]) / den - trans[i*3+1];
        float m2 = (pa[base+2] + pb[base+2]) / den - trans[i*3+2];
        const float* R = rots + (size_t)i*9;
        float r0v = R[0]*m0 + R[3]*m1 + R[6]*m2;
        float r1v = R[1]*m0 + R[4]*m1 + R[7]*m2;
        float r2v = R[2]*m0 + R[5]*m1 + R[8]*m2;
        float nrm = sqrtf(r0v*r0v + r1v*r1v + r2v*r2v + 1e-20f);
        int hv = h*8 + v;
        OF[ofb + 192 + hv] = f2bf(r0v);
        OF[ofb + 288 + hv] = f2bf(r1v);
        OF[ofb + 384 + hv] = f2bf(r2v);
        OF[ofb + 480 + hv] = f2bf(nrm);
    }
    for (int u = t; u < 1536; u += 256) {
        OF[ofb + 576 + u] = f2bf((pa[480 + u] + pb[480 + u]) / den_s[u >> 7]);
    }
}

// ---------------------------------------------------------------------------
// Kernel 4: out = OF(bf16) @ Wo (f32), K-split partials (deterministic).
// ---------------------------------------------------------------------------
__global__ __launch_bounds__(256) void out_gemm(
    const unsigned short* __restrict__ OF, const float* __restrict__ Wo,
    float* __restrict__ part)
{
    __shared__ __align__(16) float aT[32 * 132];
    __shared__ __align__(16) float bt[32 * 68];
    const int t  = threadIdx.x;
    const int i0 = blockIdx.x * 128;
    const int c0 = blockIdx.y * 64;
    const int k0 = blockIdx.z * 352;
    const int r0 = (t & 15) * 8;
    const int c4 = (t >> 4) * 4;

    float acc[8][4] = {};

    for (int kt = 0; kt < 11; kt++) {
        const int kk0 = k0 + kt*32;
        __syncthreads();
        {
            int r = t >> 1, kh = (t & 1) * 16;
            const unsigned short* apg = OF + (size_t)(i0 + r)*2112 + kk0 + kh;
            short8 v0 = *(const short8*)apg;
            short8 v1 = *(const short8*)(apg + 8);
            #pragma unroll
            for (int e = 0; e < 8; e++) aT[(kh + e)*132 + r]     = bf2f((unsigned short)v0[e]);
            #pragma unroll
            for (int e = 0; e < 8; e++) aT[(kh + 8 + e)*132 + r] = bf2f((unsigned short)v1[e]);
        }
        {
            int k = t >> 3, c8 = (t & 7) * 8;
            const float* wpg = Wo + (size_t)(kk0 + k)*384 + c0 + c8;
            *(float4*)&bt[k*68 + c8]     = *(const float4*)wpg;
            *(float4*)&bt[k*68 + c8 + 4] = *(const float4*)(wpg + 4);
        }
        __syncthreads();
        #pragma unroll 4
        for (int kk = 0; kk < 32; kk++) {
            float4 a0 = *(float4*)&aT[kk*132 + r0];
            float4 a1 = *(float4*)&aT[kk*132 + r0 + 4];
            float4 bv = *(float4*)&bt[kk*68 + c4];
            #pragma unroll
            for (int ci = 0; ci < 4; ci++) {
                float b = ((const float*)&bv)[ci];
                acc[0][ci] += ((const float*)&a0)[0] * b;
                acc[1][ci] += ((const float*)&a0)[1] * b;
                acc[2][ci] += ((const float*)&a0)[2] * b;
                acc[3][ci] += ((const float*)&a0)[3] * b;
                acc[4][ci] += ((const float*)&a1)[0] * b;
                acc[5][ci] += ((const float*)&a1)[1] * b;
                acc[6][ci] += ((const float*)&a1)[2] * b;
                acc[7][ci] += ((const float*)&a1)[3] * b;
            }
        }
    }

    float* pbv = part + (size_t)blockIdx.z * 294912;
    #pragma unroll
    for (int ri = 0; ri < 8; ri++) {
        float4 o = {acc[ri][0], acc[ri][1], acc[ri][2], acc[ri][3]};
        *(float4*)&pbv[(size_t)(i0 + r0 + ri)*384 + c0 + c4] = o;
    }
}

// ---------------------------------------------------------------------------
// Kernel 5: reduce 6 K-split partials + bias -> out (f32)
// ---------------------------------------------------------------------------
__global__ __launch_bounds__(256) void reduce_out(
    const float* __restrict__ part, const float* __restrict__ bo,
    float* __restrict__ out)
{
    int idx = blockIdx.x * 256 + threadIdx.x;
    float v = bo[idx % 384];
    #pragma unroll
    for (int s = 0; s < 6; s++) v += part[(size_t)s * 294912 + idx];
    out[idx] = v;
}

// ---------------------------------------------------------------------------
extern "C" void kernel_launch(void* const* d_in, const int* in_sizes, int n_in,
                              void* d_out, int out_size, void* d_ws, size_t ws_size,
                              hipStream_t stream) {
    const float* s     = (const float*)d_in[0];
    const float* z     = (const float*)d_in[1];
    const float* rots  = (const float*)d_in[2];
    const float* trans = (const float*)d_in[3];
    const float* mask  = (const float*)d_in[4];
    const float* Wq    = (const float*)d_in[5];
    const float* bq    = (const float*)d_in[6];
    const float* Wkv   = (const float*)d_in[7];
    const float* bkv   = (const float*)d_in[8];
    const float* Wq3   = (const float*)d_in[9];
    const float* bq3   = (const float*)d_in[10];
    const float* Wkv3  = (const float*)d_in[11];
    const float* bkv3  = (const float*)d_in[12];
    const float* Wb    = (const float*)d_in[13];
    const float* bb    = (const float*)d_in[14];
    const float* hw    = (const float*)d_in[15];
    const float* Wo    = (const float*)d_in[16];
    const float* bo    = (const float*)d_in[17];
    float* out = (float*)d_out;

    char* ws = (char*)d_ws;
    float*          Qw   = (float*)(ws + 0);
    float*          Q3w  = (float*)(ws + 589824);
    unsigned short* Kw   = (unsigned short*)(ws + 1032192);
    unsigned short* Vw   = (unsigned short*)(ws + 1327104);
    unsigned short* K3w  = (unsigned short*)(ws + 1622016);
    unsigned short* V3w  = (unsigned short*)(ws + 1843200);
    float*          P3q  = (float*)(ws + 2433024);
    float*          P3kv = (float*)(ws + 2875392);
    unsigned short* OF   = (unsigned short*)(ws + 4202496);
    // part3 (ipa partials, 1536*2048*4 = 12.58 MB) and out_gemm part
    // (6*294912*4 = 7.08 MB) are live at disjoint times -> share region.
    float*          part3 = (float*)(ws + 7446528);
    float*          part  = (float*)(ws + 7446528);

    proj_kernel<<<dim3(24, 9), 256, 0, stream>>>(
        s, Wq, bq, Wkv, bkv, Wq3, bq3, Wkv3, bkv3, Qw, Kw, Vw, P3q, P3kv);
    rot3_kernel<<<768, 192, 0, stream>>>(P3q, P3kv, rots, trans, Q3w, K3w, V3w);
    ipa_main<<<1536, 256, 0, stream>>>(
        z, mask, Wb, bb, hw, Qw, Kw, Vw, Q3w, K3w, V3w, part3);
    combine_kernel<<<768, 256, 0, stream>>>(part3, rots, trans, OF);
    out_gemm<<<dim3(6, 6, 6), 256, 0, stream>>>(OF, Wo, part);
    reduce_out<<<1152, 256, 0, stream>>>(part, bo, out);
}

// Round 4
// 258.366 us; speedup vs baseline: 1.6108x; 1.6108x over previous
//
#include <hip/hip_runtime.h>
#include <cstdint>

// ---------------------------------------------------------------------------
// InvariantPointAttention fused kernel set for MI355X (gfx950)
// N=768, C_S=384, C_Z=128, C_IPA=16, H=12, NQ=4, NV=8
// ---------------------------------------------------------------------------

typedef __attribute__((ext_vector_type(8))) short short8;
typedef __attribute__((ext_vector_type(4))) short short4_t;
typedef __attribute__((ext_vector_type(4))) float f32x4;

__device__ __forceinline__ unsigned short f2bf(float f) {
    unsigned u = __float_as_uint(f);
    u = (u + 0x7FFFu + ((u >> 16) & 1u)) >> 16;   // RNE
    return (unsigned short)u;
}
__device__ __forceinline__ float bf2f(unsigned short s) {
    return __uint_as_float(((unsigned)s) << 16);
}
__device__ __forceinline__ unsigned pk2(float lo, float hi) {
    return (unsigned)f2bf(lo) | ((unsigned)f2bf(hi) << 16);
}
// subtile placement offset: H[g] = {0,6,20,26}; 44*H[g] mod 32 = {0,8,16,24}
__device__ __forceinline__ int HOFF(int gg) {
    return gg * 6 + ((gg & 2) << 2);
}

// ---------------------------------------------------------------------------
// Kernel 1: fused projection GEMM.  s (768x384) @ [Wq|Wkv|Wq3|Wkv3] (384x1152)
// ---------------------------------------------------------------------------
__global__ __launch_bounds__(256) void proj_kernel(
    const float* __restrict__ s,
    const float* __restrict__ Wq,   const float* __restrict__ bq,
    const float* __restrict__ Wkv,  const float* __restrict__ bkv,
    const float* __restrict__ Wq3,  const float* __restrict__ bq3,
    const float* __restrict__ Wkv3, const float* __restrict__ bkv3,
    float* __restrict__ Qw, unsigned short* __restrict__ Kw,
    unsigned short* __restrict__ Vw,
    float* __restrict__ P3q, float* __restrict__ P3kv)
{
    __shared__ __align__(16) float s_lds[32 * 384];
    const int t  = threadIdx.x;
    const int r0 = blockIdx.x * 32;
    const int c0 = blockIdx.y * 128;

    for (int u = t; u < 3072; u += 256) {
        int r = u / 96, c4 = u - r * 96;
        *(float4*)&s_lds[r * 384 + c4 * 4] =
            *(const float4*)&s[(size_t)(r0 + r) * 384 + c4 * 4];
    }
    __syncthreads();

    const int rg = t >> 6;
    const int lc = t & 63;
    const int colA = c0 + lc;
    const int colB = c0 + lc + 64;

    const float *wpA, *wpB; int ldA, ldB; float biasA, biasB;
    {
        int col = colA;
        if (col < 192)      { wpA = Wq   + col;       ldA = 192; biasA = bq[col]; }
        else if (col < 576) { wpA = Wkv  + (col-192); ldA = 384; biasA = bkv[col-192]; }
        else if (col < 720) { wpA = Wq3  + (col-576); ldA = 144; biasA = bq3[col-576]; }
        else                { wpA = Wkv3 + (col-720); ldA = 432; biasA = bkv3[col-720]; }
        col = colB;
        if (col < 192)      { wpB = Wq   + col;       ldB = 192; biasB = bq[col]; }
        else if (col < 576) { wpB = Wkv  + (col-192); ldB = 384; biasB = bkv[col-192]; }
        else if (col < 720) { wpB = Wq3  + (col-576); ldB = 144; biasB = bq3[col-576]; }
        else                { wpB = Wkv3 + (col-720); ldB = 432; biasB = bkv3[col-720]; }
    }

    float acc0[8] = {}, acc1[8] = {};
    for (int k = 0; k < 384; k += 4) {
        float4 sv[8];
        #pragma unroll
        for (int r = 0; r < 8; r++)
            sv[r] = *(const float4*)&s_lds[(rg*8 + r) * 384 + k];
        #pragma unroll
        for (int kk = 0; kk < 4; kk++) {
            float w0 = wpA[(k + kk) * ldA];
            float w1 = wpB[(k + kk) * ldB];
            #pragma unroll
            for (int r = 0; r < 8; r++) {
                float sval = ((const float*)&sv[r])[kk];
                acc0[r] += sval * w0;
                acc1[r] += sval * w1;
            }
        }
    }

    #pragma unroll
    for (int q = 0; q < 2; q++) {
        int col   = q ? colB : colA;
        float bia = q ? biasB : biasA;
        #pragma unroll
        for (int r = 0; r < 8; r++) {
            int row = r0 + rg*8 + r;
            float v = (q ? acc1[r] : acc0[r]) + bia;
            if (col < 192) {
                Qw[(size_t)row*192 + col] = v;
            } else if (col < 576) {
                int c = col - 192, h = c >> 5, sub = c & 31;
                if (sub < 16) Kw[(size_t)row*192 + h*16 + sub]      = f2bf(v);
                else          Vw[(size_t)row*192 + h*16 + (sub-16)] = f2bf(v);
            } else if (col < 720) {
                P3q[(size_t)row*144 + (col-576)] = v;
            } else {
                P3kv[(size_t)row*432 + (col-720)] = v;
            }
        }
    }
}

// ---------------------------------------------------------------------------
// Kernel 2: rotate/translate projected points.
// ---------------------------------------------------------------------------
__global__ __launch_bounds__(192) void rot3_kernel(
    const float* __restrict__ P3q, const float* __restrict__ P3kv,
    const float* __restrict__ rots, const float* __restrict__ trans,
    float* __restrict__ Q3w, unsigned short* __restrict__ K3w,
    unsigned short* __restrict__ V3w)
{
    const int n = blockIdx.x;
    const int t = threadIdx.x;
    float R[9];
    #pragma unroll
    for (int u = 0; u < 9; u++) R[u] = rots[n*9 + u];
    float T0 = trans[n*3+0], T1 = trans[n*3+1], T2 = trans[n*3+2];

    float p0, p1, p2;
    if (t < 48) {
        p0 = P3q[(size_t)n*144 + t];
        p1 = P3q[(size_t)n*144 + 48 + t];
        p2 = P3q[(size_t)n*144 + 96 + t];
    } else {
        int k = t - 48;
        p0 = P3kv[(size_t)n*432 + k];
        p1 = P3kv[(size_t)n*432 + 144 + k];
        p2 = P3kv[(size_t)n*432 + 288 + k];
    }
    float o0 = R[0]*p0 + R[1]*p1 + R[2]*p2 + T0;
    float o1 = R[3]*p0 + R[4]*p1 + R[5]*p2 + T1;
    float o2 = R[6]*p0 + R[7]*p1 + R[8]*p2 + T2;

    if (t < 48) {
        Q3w[(size_t)n*144 + t*3 + 0] = o0;
        Q3w[(size_t)n*144 + t*3 + 1] = o1;
        Q3w[(size_t)n*144 + t*3 + 2] = o2;
    } else {
        int k = t - 48, h = k / 12, m = k % 12;
        if (m < 4) {
            size_t base = (size_t)n*144 + (h*4 + m)*3;
            K3w[base+0] = f2bf(o0); K3w[base+1] = f2bf(o1); K3w[base+2] = f2bf(o2);
        } else {
            size_t base = (size_t)n*384 + (h*8 + (m-4))*4;
            V3w[base+0] = f2bf(o0); V3w[base+1] = f2bf(o1); V3w[base+2] = f2bf(o2);
        }
    }
}

// ---------------------------------------------------------------------------
// Kernel 3: fused IPA attention, j-split x2 (exact partials).
// grid 1536: block = (i, chunk).  12 z-tiles of 32 j each.
// z subtiles [4][16] bf16 at stride 88 elems, PLACED at slot S + H[S>>4]
// (H = {0,6,20,26}) so phase-C's 4 lane-groups hit disjoint 8-bank windows.
// Partial layout per block (stride 2560 f32):
//   [0:192) O | [192:480) O3 slotA | [480:768) O3 slotB (h>=8 only) |
//   [768:2304) Opair | [2304:2316) den
// ---------------------------------------------------------------------------
__global__ __launch_bounds__(256, 4) void ipa_main(
    const float* __restrict__ z, const float* __restrict__ mask,
    const float* __restrict__ Wb, const float* __restrict__ bb,
    const float* __restrict__ hw,
    const float* __restrict__ Qw, const unsigned short* __restrict__ Kw,
    const unsigned short* __restrict__ Vw,
    const float* __restrict__ Q3w, const unsigned short* __restrict__ K3w,
    const unsigned short* __restrict__ V3w,
    float* __restrict__ part3)
{
    __shared__ __align__(16) unsigned short z_l[90 * 88];     // 15.8 KB
    __shared__ __align__(16) unsigned short wbT_l[16 * 136];
    __shared__ __align__(16) float          p_l[32 * 17];
    __shared__ __align__(16) unsigned short pT_l[16 * 40];
    __shared__ __align__(16) float          Q_lds[192];
    __shared__ __align__(16) float          Q3_lds[144];
    __shared__ float hw_lds[12], bb_lds[12];

    const int i     = blockIdx.x >> 1;
    const int chunk = blockIdx.x & 1;
    const int t    = threadIdx.x;
    const int lane = t & 63;
    const int wv   = t >> 6;
    const int g    = lane >> 4;
    const int lm   = lane & 15;

    // ------- per-block init -------
    if (t < 192) Q_lds[t]  = Qw[(size_t)i*192 + t];
    if (t < 144) Q3_lds[t] = Q3w[(size_t)i*144 + t];
    if (t < 12) {
        hw_lds[t] = log1pf(__expf(hw[t])) * 0.13608276348795434f;
        bb_lds[t] = bb[t];
    }
    if (t < 160) pT_l[480 + t] = 0;
    for (int u = t; u < 1536; u += 256) {
        int h = u % 12, c = u / 12;
        wbT_l[h*136 + c] = f2bf(Wb[c*12 + h]);
    }
    const float mask_i = mask[i];

    // accumulators
    f32x4 opA = {0,0,0,0}, opB = {0,0,0,0};
    float oacc = 0.0f;
    float o3x = 0, o3y = 0, o3z = 0;
    float dena = 0;
    const int oh = t >> 4, oc = t & 15;
    // O3 work split: t>=192 -> h 0..7 full j; t<32 -> h 8..11 j 0..15;
    // t in [32,64) -> h 8..11 j 16..31 (slot B)
    int o3h = -1, o3v = 0, o3j0 = 0, o3j1 = 32, o3slot = 0;
    if (t >= 192)    { o3h = (t - 192) >> 3;      o3v = (t - 192) & 7; }
    else if (t < 32) { o3h = 8 + (t >> 3);        o3v = t & 7;        o3j1 = 16; }
    else if (t < 64) { o3h = 8 + ((t - 32) >> 3); o3v = (t - 32) & 7; o3j0 = 16; o3slot = 1; }
    const int denh = (t >= 64 && t < 76) ? (t - 64) : -1;

    const int jj  = t >> 3, c16 = t & 7;
    const float* zbase = z + ((size_t)i*768 + chunk*384 + jj)*128 + c16*16;
    const int chS  = (jj >> 2)*8 + c16;                 // subtile 0..63
    const int chP  = chS + HOFF(chS >> 4);              // placed slot
    const int sidx = chP*88 + (jj & 3)*16;              // element index

    __syncthreads();

    for (int tile = 0; tile < 12; tile++) {
        const int j0 = chunk*384 + tile*32;

        // ---- phase A: load z tile, convert, store placed-subtile LDS ----
        {
            const float* zp = zbase + (size_t)tile * 32 * 128;
            float4 f0 = *(const float4*)(zp + 0);
            float4 f1 = *(const float4*)(zp + 4);
            float4 f2 = *(const float4*)(zp + 8);
            float4 f3 = *(const float4*)(zp + 12);
            uint4* dst = (uint4*)&z_l[sidx];
            dst[0] = uint4{pk2(f0.x,f0.y), pk2(f0.z,f0.w), pk2(f1.x,f1.y), pk2(f1.z,f1.w)};
            dst[1] = uint4{pk2(f2.x,f2.y), pk2(f2.z,f2.w), pk2(f3.x,f3.y), pk2(f3.z,f3.w)};
        }
        __syncthreads();

        // ---- phase B1: B = z@Wb via MFMA, waves 0 and 1 ----
        if (wv < 2) {
            f32x4 ab = {0,0,0,0};
            const int jt = wv;
            #pragma unroll
            for (int ks = 0; ks < 4; ks++) {
                short8 bf = *(const short8*)&wbT_l[lm*136 + ks*32 + g*8];
                int jr = jt*16 + lm;
                int ch = (jr >> 2)*8 + ks*2 + (g >> 1);
                int cp = ch + HOFF(ch >> 4);
                short8 a = *(const short8*)&z_l[cp*88 + (jr & 3)*16 + (g & 1)*8];
                ab = __builtin_amdgcn_mfma_f32_16x16x32_bf16(a, bf, ab, 0, 0, 0);
            }
            if (lm < 12) {
                #pragma unroll
                for (int r = 0; r < 4; r++)
                    p_l[(jt*16 + g*4 + r)*17 + lm] = ab[r];
            }
        }
        __syncthreads();

        // ---- phase B2: finish logits, exp, store p (f32) and p^T (bf16) ----
        #pragma unroll
        for (int rep = 0; rep < 2; rep++) {
            int pr = t + rep*256;
            if (pr < 384) {
                int jjq = pr / 12;
                int h   = pr - jjq*12;
                int j   = j0 + jjq;
                float Bv = p_l[jjq*17 + h];
                const unsigned short* kp = Kw + (size_t)j*192 + h*16;
                short8 kA = *(const short8*)(kp);
                short8 kB = *(const short8*)(kp + 8);
                float qk = 0.0f;
                #pragma unroll
                for (int e = 0; e < 8; e++) qk += Q_lds[h*16 + e]     * bf2f((unsigned short)kA[e]);
                #pragma unroll
                for (int e = 0; e < 8; e++) qk += Q_lds[h*16 + 8 + e] * bf2f((unsigned short)kB[e]);
                const unsigned short* k3p = K3w + (size_t)j*144 + h*12;
                short4_t c0v = *(const short4_t*)(k3p);
                short4_t c1v = *(const short4_t*)(k3p + 4);
                short4_t c2v = *(const short4_t*)(k3p + 8);
                float d2 = 0.0f;
                #pragma unroll
                for (int e = 0; e < 4; e++) { float d = Q3_lds[h*12 + e]     - bf2f((unsigned short)c0v[e]); d2 += d*d; }
                #pragma unroll
                for (int e = 0; e < 4; e++) { float d = Q3_lds[h*12 + 4 + e] - bf2f((unsigned short)c1v[e]); d2 += d*d; }
                #pragma unroll
                for (int e = 0; e < 4; e++) { float d = Q3_lds[h*12 + 8 + e] - bf2f((unsigned short)c2v[e]); d2 += d*d; }
                float mj = mask[j];
                float lg = qk * 0.14433756729740643f
                         + (Bv + bb_lds[h]) * 0.5773502691896258f
                         - 0.5f * hw_lds[h] * d2
                         + (mask_i * mj - 1.0f) * 1e9f;
                float p = __expf(lg);
                p_l[jjq*17 + h]  = p;
                pT_l[h*40 + jjq] = f2bf(p);
            }
        }
        __syncthreads();

        // ---- phase C: O_pair MFMA (conflict-free placed subtiles) ----
        {
            const int nt0 = wv*2;
            short8 ap = *(const short8*)((const char*)pT_l + lm*80 + g*16);
            short8 b0, b1;
            #pragma unroll
            for (int e = 0; e < 8; e++) {
                int jje = g*8 + e;
                int su  = (jje >> 2)*8;
                int ro  = (jje & 3)*16;
                int cp0 = su + nt0 + HOFF(g);       // (su+nt0)>>4 == g
                b0[e] = (short)z_l[cp0*88 + ro + lm];
                b1[e] = (short)z_l[(cp0 + 1)*88 + ro + lm];
            }
            opA = __builtin_amdgcn_mfma_f32_16x16x32_bf16(ap, b0, opA, 0, 0, 0);
            opB = __builtin_amdgcn_mfma_f32_16x16x32_bf16(ap, b1, opB, 0, 0, 0);
        }
        if (t < 192) {
            #pragma unroll 8
            for (int jjq = 0; jjq < 32; jjq++) {
                float p = p_l[jjq*17 + oh];
                oacc += p * bf2f(Vw[(size_t)(j0 + jjq)*192 + oh*16 + oc]);
            }
        }
        if (o3h >= 0) {
            #pragma unroll 8
            for (int jjq = o3j0; jjq < o3j1; jjq++) {
                float p = p_l[jjq*17 + o3h];
                short4_t v4 = *(const short4_t*)(V3w + (size_t)(j0 + jjq)*384 + (o3h*8 + o3v)*4);
                o3x += p * bf2f((unsigned short)v4[0]);
                o3y += p * bf2f((unsigned short)v4[1]);
                o3z += p * bf2f((unsigned short)v4[2]);
            }
        }
        if (denh >= 0) {
            #pragma unroll 8
            for (int jjq = 0; jjq < 32; jjq++) dena += p_l[jjq*17 + denh];
        }
        __syncthreads();
    }

    // ------- write partials -------
    float* pb = part3 + (size_t)blockIdx.x * 2560;
    if (t < 192) pb[t] = oacc;
    if (o3h >= 0) {
        int base = 192 + o3slot*288 + (o3h*8 + o3v)*3;
        pb[base+0] = o3x; pb[base+1] = o3y; pb[base+2] = o3z;
    }
    if (denh >= 0) pb[2304 + denh] = dena;
    {
        const int nt0 = wv*2;
        #pragma unroll
        for (int r = 0; r < 4; r++) {
            int h = g*4 + r;
            if (h < 12) {
                pb[768 + h*128 + nt0*16 + lm]       = opA[r];
                pb[768 + h*128 + (nt0 + 1)*16 + lm] = opB[r];
            }
        }
    }
}

// ---------------------------------------------------------------------------
// Kernel 3b: combine 2 j-chunks, divide by den, rotate O3, write OF row.
// ---------------------------------------------------------------------------
__global__ __launch_bounds__(256) void combine_kernel(
    const float* __restrict__ part3, const float* __restrict__ rots,
    const float* __restrict__ trans, unsigned short* __restrict__ OF)
{
    const int i = blockIdx.x;
    const int t = threadIdx.x;
    const float* pa = part3 + (size_t)i*2*2560;
    const float* pb = pa + 2560;
    __shared__ float den_s[12];
    if (t < 12) den_s[t] = pa[2304 + t] + pb[2304 + t];
    __syncthreads();

    const size_t ofb = (size_t)i * 2112;
    if (t < 192) OF[ofb + t] = f2bf((pa[t] + pb[t]) / den_s[t >> 4]);
    if (t < 96) {
        int h = t >> 3, v = t & 7;
        float den = den_s[h];
        int base = 192 + t*3;
        float m0 = pa[base+0] + pb[base+0];
        float m1 = pa[base+1] + pb[base+1];
        float m2 = pa[base+2] + pb[base+2];
        if (h >= 8) {   // slot B contributions (j 16..31 halves)
            m0 += pa[base+288+0] + pb[base+288+0];
            m1 += pa[base+288+1] + pb[base+288+1];
            m2 += pa[base+288+2] + pb[base+288+2];
        }
        m0 = m0 / den - trans[i*3+0];
        m1 = m1 / den - trans[i*3+1];
        m2 = m2 / den - trans[i*3+2];
        const float* R = rots + (size_t)i*9;
        float r0v = R[0]*m0 + R[3]*m1 + R[6]*m2;
        float r1v = R[1]*m0 + R[4]*m1 + R[7]*m2;
        float r2v = R[2]*m0 + R[5]*m1 + R[8]*m2;
        float nrm = sqrtf(r0v*r0v + r1v*r1v + r2v*r2v + 1e-20f);
        int hv = h*8 + v;
        OF[ofb + 192 + hv] = f2bf(r0v);
        OF[ofb + 288 + hv] = f2bf(r1v);
        OF[ofb + 384 + hv] = f2bf(r2v);
        OF[ofb + 480 + hv] = f2bf(nrm);
    }
    for (int u = t; u < 1536; u += 256) {
        OF[ofb + 576 + u] = f2bf((pa[768 + u] + pb[768 + u]) / den_s[u >> 7]);
    }
}

// ---------------------------------------------------------------------------
// Kernel 4: out = OF(bf16) @ Wo (f32), K-split partials (deterministic).
// ---------------------------------------------------------------------------
__global__ __launch_bounds__(256) void out_gemm(
    const unsigned short* __restrict__ OF, const float* __restrict__ Wo,
    float* __restrict__ part)
{
    __shared__ __align__(16) float aT[32 * 132];
    __shared__ __align__(16) float bt[32 * 68];
    const int t  = threadIdx.x;
    const int i0 = blockIdx.x * 128;
    const int c0 = blockIdx.y * 64;
    const int k0 = blockIdx.z * 352;
    const int r0 = (t & 15) * 8;
    const int c4 = (t >> 4) * 4;

    float acc[8][4] = {};

    for (int kt = 0; kt < 11; kt++) {
        const int kk0 = k0 + kt*32;
        __syncthreads();
        {
            int r = t >> 1, kh = (t & 1) * 16;
            const unsigned short* apg = OF + (size_t)(i0 + r)*2112 + kk0 + kh;
            short8 v0 = *(const short8*)apg;
            short8 v1 = *(const short8*)(apg + 8);
            #pragma unroll
            for (int e = 0; e < 8; e++) aT[(kh + e)*132 + r]     = bf2f((unsigned short)v0[e]);
            #pragma unroll
            for (int e = 0; e < 8; e++) aT[(kh + 8 + e)*132 + r] = bf2f((unsigned short)v1[e]);
        }
        {
            int k = t >> 3, c8 = (t & 7) * 8;
            const float* wpg = Wo + (size_t)(kk0 + k)*384 + c0 + c8;
            *(float4*)&bt[k*68 + c8]     = *(const float4*)wpg;
            *(float4*)&bt[k*68 + c8 + 4] = *(const float4*)(wpg + 4);
        }
        __syncthreads();
        #pragma unroll 4
        for (int kk = 0; kk < 32; kk++) {
            float4 a0 = *(float4*)&aT[kk*132 + r0];
            float4 a1 = *(float4*)&aT[kk*132 + r0 + 4];
            float4 bv = *(float4*)&bt[kk*68 + c4];
            #pragma unroll
            for (int ci = 0; ci < 4; ci++) {
                float b = ((const float*)&bv)[ci];
                acc[0][ci] += ((const float*)&a0)[0] * b;
                acc[1][ci] += ((const float*)&a0)[1] * b;
                acc[2][ci] += ((const float*)&a0)[2] * b;
                acc[3][ci] += ((const float*)&a0)[3] * b;
                acc[4][ci] += ((const float*)&a1)[0] * b;
                acc[5][ci] += ((const float*)&a1)[1] * b;
                acc[6][ci] += ((const float*)&a1)[2] * b;
                acc[7][ci] += ((const float*)&a1)[3] * b;
            }
        }
    }

    float* pbv = part + (size_t)blockIdx.z * 294912;
    #pragma unroll
    for (int ri = 0; ri < 8; ri++) {
        float4 o = {acc[ri][0], acc[ri][1], acc[ri][2], acc[ri][3]};
        *(float4*)&pbv[(size_t)(i0 + r0 + ri)*384 + c0 + c4] = o;
    }
}

// ---------------------------------------------------------------------------
// Kernel 5: reduce 6 K-split partials + bias -> out (f32)
// ---------------------------------------------------------------------------
__global__ __launch_bounds__(256) void reduce_out(
    const float* __restrict__ part, const float* __restrict__ bo,
    float* __restrict__ out)
{
    int idx = blockIdx.x * 256 + threadIdx.x;
    float v = bo[idx % 384];
    #pragma unroll
    for (int s = 0; s < 6; s++) v += part[(size_t)s * 294912 + idx];
    out[idx] = v;
}

// ---------------------------------------------------------------------------
extern "C" void kernel_launch(void* const* d_in, const int* in_sizes, int n_in,
                              void* d_out, int out_size, void* d_ws, size_t ws_size,
                              hipStream_t stream) {
    const float* s     = (const float*)d_in[0];
    const float* z     = (const float*)d_in[1];
    const float* rots  = (const float*)d_in[2];
    const float* trans = (const float*)d_in[3];
    const float* mask  = (const float*)d_in[4];
    const float* Wq    = (const float*)d_in[5];
    const float* bq    = (const float*)d_in[6];
    const float* Wkv   = (const float*)d_in[7];
    const float* bkv   = (const float*)d_in[8];
    const float* Wq3   = (const float*)d_in[9];
    const float* bq3   = (const float*)d_in[10];
    const float* Wkv3  = (const float*)d_in[11];
    const float* bkv3  = (const float*)d_in[12];
    const float* Wb    = (const float*)d_in[13];
    const float* bb    = (const float*)d_in[14];
    const float* hw    = (const float*)d_in[15];
    const float* Wo    = (const float*)d_in[16];
    const float* bo    = (const float*)d_in[17];
    float* out = (float*)d_out;

    char* ws = (char*)d_ws;
    float*          Qw   = (float*)(ws + 0);
    float*          Q3w  = (float*)(ws + 589824);
    unsigned short* Kw   = (unsigned short*)(ws + 1032192);
    unsigned short* Vw   = (unsigned short*)(ws + 1327104);
    unsigned short* K3w  = (unsigned short*)(ws + 1622016);
    unsigned short* V3w  = (unsigned short*)(ws + 1843200);
    float*          P3q  = (float*)(ws + 2433024);
    float*          P3kv = (float*)(ws + 2875392);
    unsigned short* OF   = (unsigned short*)(ws + 4202496);
    // part3 (ipa partials, 1536*2560*4 = 15.7 MB) and out_gemm part
    // (7.08 MB) are live at disjoint times -> share region.
    float*          part3 = (float*)(ws + 7446528);
    float*          part  = (float*)(ws + 7446528);

    proj_kernel<<<dim3(24, 9), 256, 0, stream>>>(
        s, Wq, bq, Wkv, bkv, Wq3, bq3, Wkv3, bkv3, Qw, Kw, Vw, P3q, P3kv);
    rot3_kernel<<<768, 192, 0, stream>>>(P3q, P3kv, rots, trans, Q3w, K3w, V3w);
    ipa_main<<<1536, 256, 0, stream>>>(
        z, mask, Wb, bb, hw, Qw, Kw, Vw, Q3w, K3w, V3w, part3);
    combine_kernel<<<768, 256, 0, stream>>>(part3, rots, trans, OF);
    out_gemm<<<dim3(6, 6, 6), 256, 0, stream>>>(OF, Wo, part);
    reduce_out<<<1152, 256, 0, stream>>>(part, bo, out);
}